// Round 7
// baseline (1662.708 us; speedup 1.0000x reference)
//
#include <hip/hip_runtime.h>
#include <stdint.h>
#include <math.h>

// RNN predictor: B=2048, T=1024 teacher-forced + FUT=64 autoregressive, H=128.
// Round-7: R6 structure, but BUILTIN MFMA (compiler-managed hazards — R6's
// inline-asm MFMA NaN'd because LLVM inserts no wait-states around INLINEASM)
// and a register budget that fits 2 waves/SIMD:
//  - SPB=4, 512 blocks -> 2 blocks/CU; __launch_bounds__(256,2) caps unified
//    regs at 256/wave: weights 128 + A 32 + accs ~20 + misc ~40 fits -> all
//    arch VGPRs, no AGPR operand copies (R5's 625 VALU/step).
//  - packed (hi|lo) u32 h state + W1=interleave(hi,lo), W2=interleave(lo,hi)
//    => all 4 split products via 2 MFMA chains/tile (verified R5).
//  - o = W_out.h via MFMA against already-loaded A-frags; Wo staged in LDS,
//    only wave (i&3) computes it in teacher phase, all waves in AR phase.
//  - A-fragment registers zeroed BEFORE the loop; exec-masked ds_read keeps
//    inactive lanes' zeros (no per-step re-init).
//  - one barrier per step; o buffered in a 64-entry LDS ring, flushed f32x4.

#define TLEN  1024
#define FUT   64
#define HID   128
#define SPB   4
#define NT    256
#define NSTEP (TLEN + FUT)

typedef float f32x4 __attribute__((ext_vector_type(4)));
typedef uint32_t u32x4 __attribute__((ext_vector_type(4)));
typedef short bf16x8 __attribute__((ext_vector_type(8)));

__device__ __forceinline__ bf16x8 asbf(u32x4 v) {
    return __builtin_bit_cast(bf16x8, v);
}
__device__ __forceinline__ float fast_tanh(float v) {
    return 1.0f - 2.0f / (__expf(2.0f * v) + 1.0f);   // saturates correctly
}
__device__ __forceinline__ unsigned short bf16_rn(float f) {
    uint32_t u = __builtin_bit_cast(uint32_t, f);
    uint32_t r = (u + 0x7fffu + ((u >> 16) & 1u)) >> 16;  // RNE
    return (unsigned short)r;
}
__device__ __forceinline__ float bf16f(unsigned short h) {
    uint32_t u = (uint32_t)h << 16;
    return __builtin_bit_cast(float, u);
}

__global__ __launch_bounds__(NT, 2) void rnn_kernel(
    const float* __restrict__ x,      // [B, T]
    const float* __restrict__ W_ih,   // [H, 1]
    const float* __restrict__ W_hh,   // [H, H]
    const float* __restrict__ b_ih,   // [H]
    const float* __restrict__ b_hh,   // [H]
    const float* __restrict__ W_out,  // [1, H]
    const float* __restrict__ b_out,  // [1]
    float* __restrict__ out)          // [B, T+FUT]
{
    __shared__ __align__(16) uint32_t hbuf[2][SPB * HID];   // packed (hi|lo), swizzled
    __shared__ __align__(16) float xstg[128][8];            // x chunk (cols 0..3 used)
    __shared__ __align__(16) float outbuf[2][SPB][68];      // o ring, padded
    __shared__ __align__(16) uint32_t wo_lds[HID];          // packed W_out

    const int tid  = threadIdx.x;
    const int lane = tid & 63;
    const int wid  = tid >> 6;        // wave w: owns cols 32w..32w+31
    const int l15  = lane & 15;
    const int g    = lane >> 4;       // lane quarter
    const int s0   = blockIdx.x * SPB;

    // ---- weight fragments (packed hi|lo), 128 VGPRs ----
    // Slot map (A and B identical): G, slot s=8g+e -> real k=16G+4g+(e>>1),
    // parity e&1 selects hi/lo. W1 u32 = hi|lo<<16, W2 = lo|hi<<16.
    const int j0 = wid * 32 + l15;
    const int j1 = j0 + 16;
    u32x4 W1a[8], W2a[8], W1b[8], W2b[8];
    {
        const float* r0 = W_hh + (size_t)j0 * HID;
        const float* r1 = W_hh + (size_t)j1 * HID;
        #pragma unroll
        for (int G = 0; G < 8; ++G) {
            const int kb = G * 16 + g * 4;
            #pragma unroll
            for (int t = 0; t < 4; ++t) {
                const float wa = r0[kb + t];
                const float wb = r1[kb + t];
                const uint32_t ha = bf16_rn(wa);
                const uint32_t la = bf16_rn(wa - bf16f((unsigned short)ha));
                const uint32_t hb_ = bf16_rn(wb);
                const uint32_t lb = bf16_rn(wb - bf16f((unsigned short)hb_));
                W1a[G][t] = ha | (la << 16);
                W2a[G][t] = la | (ha << 16);
                W1b[G][t] = hb_ | (lb << 16);
                W2b[G][t] = lb | (hb_ << 16);
            }
        }
    }
    const float bias0 = b_ih[j0] + b_hh[j0];
    const float bias1 = b_ih[j1] + b_hh[j1];
    const float wih0  = W_ih[j0], wih1 = W_ih[j1];
    const float bo    = b_out[0];

    // ---- LDS byte offsets; swizzle byte ^= (row&7)<<4 (verified R5) ----
    int aoff[8];
    #pragma unroll
    for (int G = 0; G < 8; ++G)
        aoff[G] = l15 * 512 + ((G * 64 + g * 16) ^ ((l15 & 7) << 4));
    int woffA[4], woffB[4];
    #pragma unroll
    for (int r = 0; r < 4; ++r) {
        const int row = 4 * g + r;     // only g==0 rows are ever written
        const int swz = (row & 7) << 4;
        woffA[r] = row * 512 + ((4 * j0) ^ swz);
        woffB[r] = row * 512 + ((4 * j1) ^ swz);
    }

    for (int idx = tid; idx < SPB * HID; idx += NT) hbuf[0][idx] = 0;
    if (tid < HID) {
        const float wo = W_out[tid];
        const uint32_t ho = bf16_rn(wo);
        const uint32_t lo_ = bf16_rn(wo - bf16f((unsigned short)ho));
        wo_lds[tid] = ho | (lo_ << 16);
    }
    __syncthreads();

    // A-fragments: zero once; exec-masked loads keep l15>=SPB lanes at zero.
    u32x4 A_[8];
    #pragma unroll
    for (int G = 0; G < 8; ++G) A_[G] = (u32x4){0, 0, 0, 0};

    for (int i = 0; i < NSTEP; ++i) {
        const int p = i & 1;

        // refill x chunk every 128 teacher steps
        if (i < TLEN && (i & 127) == 0) {
            #pragma unroll
            for (int pass = 0; pass < 2; ++pass) {
                const int idx = pass * NT + tid;
                const int t = idx & 127, s = idx >> 7;
                xstg[t][s] = x[(size_t)(s0 + s) * TLEN + (i + t)];
            }
            __syncthreads();
        }

        // flush a full 64-entry output ring (o_{i-65}..o_{i-2})
        if (i > 64 && (i & 63) == 1 && tid < 16 * SPB) {
            const int q = ((i - 65) >> 6) & 1;
            const int base = i - 65;
            const int s = tid >> 4, c4 = (tid & 15) * 4;
            const f32x4 v = *(const f32x4*)&outbuf[q][s][c4];
            *(f32x4*)&out[(size_t)(s0 + s) * NSTEP + base + c4] = v;
        }

        // A-fragments (rows >= SPB stay zero via exec mask)
        const char* hbp = (const char*)hbuf[p];
        if (l15 < SPB) {
            #pragma unroll
            for (int G = 0; G < 8; ++G)
                A_[G] = *(const u32x4*)(hbp + aoff[G]);
        }

        // o-chain: designated wave in teacher phase, all waves in AR
        const bool doWo = (wid == (i & 3)) || (i >= TLEN);
        f32x4 oa = {0.f, 0.f, 0.f, 0.f};
        if (doWo) {
            #pragma unroll
            for (int G = 0; G < 8; ++G) {
                u32x4 wo = (u32x4){0, 0, 0, 0};
                if (l15 == 0)
                    wo = *(const u32x4*)((const char*)wo_lds + (G * 64 + g * 16));
                oa = __builtin_amdgcn_mfma_f32_16x16x32_bf16(asbf(A_[G]), asbf(wo), oa, 0, 0, 0);
            }
        }

        // 32 MFMA in 4 independent chains, operands in VGPRs
        f32x4 p10 = {0.f,0.f,0.f,0.f}, p20 = p10, p11 = p10, p21 = p10;
        #pragma unroll
        for (int G = 0; G < 8; ++G) {
            p10 = __builtin_amdgcn_mfma_f32_16x16x32_bf16(asbf(A_[G]), asbf(W1a[G]), p10, 0, 0, 0);
            p11 = __builtin_amdgcn_mfma_f32_16x16x32_bf16(asbf(A_[G]), asbf(W1b[G]), p11, 0, 0, 0);
            p20 = __builtin_amdgcn_mfma_f32_16x16x32_bf16(asbf(A_[G]), asbf(W2a[G]), p20, 0, 0, 0);
            p21 = __builtin_amdgcn_mfma_f32_16x16x32_bf16(asbf(A_[G]), asbf(W2b[G]), p21, 0, 0, 0);
        }

        // o_{i-1}: valid at lane 0 (g=0,l15=0), rows r
        if (i > 0 && lane == 0 && wid == (i < TLEN ? (i & 3) : 0)) {
            const int q = ((i - 1) >> 6) & 1;
            const int c = (i - 1) & 63;
            #pragma unroll
            for (int r = 0; r < 4; ++r) outbuf[q][r][c] = oa[r] + bo;
        }

        // per-row inputs (uniform branch)
        float in0, in1, in2, in3;
        if (i < TLEN) {
            const f32x4 xv = *(const f32x4*)&xstg[i & 127][0];
            in0 = xv[0]; in1 = xv[1]; in2 = xv[2]; in3 = xv[3];
        } else {
            in0 = __shfl(oa[0] + bo, 0);
            in1 = __shfl(oa[1] + bo, 0);
            in2 = __shfl(oa[2] + bo, 0);
            in3 = __shfl(oa[3] + bo, 0);
        }

        // epilogue: S, tanh, pack (hi|lo), masked writes (rows 0..3 at g==0)
        char* hw = (char*)hbuf[p ^ 1];
        #pragma unroll
        for (int r = 0; r < 4; ++r) {
            const float inr = (r == 0) ? in0 : (r == 1) ? in1 : (r == 2) ? in2 : in3;
            const float S0 = p10[r] + p20[r] + bias0 + inr * wih0;
            const float S1 = p11[r] + p21[r] + bias1 + inr * wih1;
            const float h0 = fast_tanh(S0);
            const float h1 = fast_tanh(S1);
            uint32_t P;
            asm("v_cvt_pk_bf16_f32 %0, %1, %2" : "=v"(P) : "v"(h0), "v"(h1));
            const float hi0 = __builtin_bit_cast(float, P << 16);
            const float hi1 = __builtin_bit_cast(float, P & 0xffff0000u);
            const float lo0 = h0 - hi0;
            const float lo1 = h1 - hi1;
            uint32_t PL;
            asm("v_cvt_pk_bf16_f32 %0, %1, %2" : "=v"(PL) : "v"(lo0), "v"(lo1));
            if (g == 0) {
                *(uint32_t*)(hw + woffA[r]) = (P & 0xffffu) | (PL << 16);
                *(uint32_t*)(hw + woffB[r]) = (P >> 16) | (PL & 0xffff0000u);
            }
        }
        __syncthreads();   // the one per-step barrier
    }

    // tail: o_{NSTEP-1} from final state (in hbuf[0])
    {
        const char* hbp = (const char*)hbuf[NSTEP & 1];
        if (l15 < SPB) {
            #pragma unroll
            for (int G = 0; G < 8; ++G)
                A_[G] = *(const u32x4*)(hbp + aoff[G]);
        }
        f32x4 oa = {0.f, 0.f, 0.f, 0.f};
        #pragma unroll
        for (int G = 0; G < 8; ++G) {
            u32x4 wo = (u32x4){0, 0, 0, 0};
            if (l15 == 0)
                wo = *(const u32x4*)((const char*)wo_lds + (G * 64 + g * 16));
            oa = __builtin_amdgcn_mfma_f32_16x16x32_bf16(asbf(A_[G]), asbf(wo), oa, 0, 0, 0);
        }
        if (tid == 0) {
            #pragma unroll
            for (int r = 0; r < 4; ++r)
                outbuf[((NSTEP - 1) >> 6) & 1][r][63] = oa[r] + bo;
        }
    }
    __syncthreads();
    if (tid < 16 * SPB) {   // flush t = 1024..1087
        const int s = tid >> 4, c4 = (tid & 15) * 4;
        const f32x4 v = *(const f32x4*)&outbuf[0][s][c4];
        *(f32x4*)&out[(size_t)(s0 + s) * NSTEP + TLEN + c4] = v;
    }
}

extern "C" void kernel_launch(void* const* d_in, const int* in_sizes, int n_in,
                              void* d_out, int out_size, void* d_ws, size_t ws_size,
                              hipStream_t stream) {
    const float* x     = (const float*)d_in[0];
    const float* W_ih  = (const float*)d_in[1];
    const float* W_hh  = (const float*)d_in[2];
    const float* b_ih  = (const float*)d_in[3];
    const float* b_hh  = (const float*)d_in[4];
    const float* W_out = (const float*)d_in[5];
    const float* b_out = (const float*)d_in[6];
    float* out = (float*)d_out;

    dim3 grid(2048 / SPB);   // 512 blocks -> 2 per CU
    dim3 block(NT);
    rnn_kernel<<<grid, block, 0, stream>>>(x, W_ih, W_hh, b_ih, b_hh,
                                           W_out, b_out, out);
}

// Round 8
// 1480.632 us; speedup vs baseline: 1.1230x; 1.1230x over previous
//
#include <hip/hip_runtime.h>
#include <stdint.h>
#include <math.h>

// RNN predictor: B=2048, T=1024 teacher-forced + FUT=64 autoregressive, H=128.
// Round-8: inline-asm MFMA with "v"-constrained operands so the 160 weight
// registers are FORCED into arch VGPRs (builtin path kept them in AGPRs and
// paid ~550 copy-VALU/step, R5/R7). Hazard handling done manually:
//  - s_nop 2 at each chain head (VALU acc-init -> MFMA SrcC: 2 wait states)
//  - 8 same-acc MFMAs back-to-back inside a chain (HW-interlocked accumulate)
//  - fence asm (s_nop 7 x3) with all accs "+v"-tied so no VALU read of an
//    MFMA D-register can be scheduled into the wait-state window.
// Structure otherwise = R7 (passed): SPB=4, 512 blocks -> 2 blocks/CU,
// packed (hi|lo) u32 h state, W1=ilv(hi,lo) + W2=ilv(lo,hi) -> 4 split
// products, o = W_out.h via MFMA (Wo register-resident, all waves compute),
// one barrier/step, 64-entry LDS output ring flushed as f32x4.

#define TLEN  1024
#define FUT   64
#define HID   128
#define SPB   4
#define NT    256
#define NSTEP (TLEN + FUT)

typedef float f32x4 __attribute__((ext_vector_type(4)));
typedef uint32_t u32x4 __attribute__((ext_vector_type(4)));
typedef short bf16x8 __attribute__((ext_vector_type(8)));

__device__ __forceinline__ bf16x8 asbf(u32x4 v) {
    return __builtin_bit_cast(bf16x8, v);
}
__device__ __forceinline__ float fast_tanh(float v) {
    return 1.0f - 2.0f / (__expf(2.0f * v) + 1.0f);   // saturates correctly
}
__device__ __forceinline__ unsigned short bf16_rn(float f) {
    uint32_t u = __builtin_bit_cast(uint32_t, f);
    uint32_t r = (u + 0x7fffu + ((u >> 16) & 1u)) >> 16;  // RNE
    return (unsigned short)r;
}
__device__ __forceinline__ float bf16f(unsigned short h) {
    uint32_t u = (uint32_t)h << 16;
    return __builtin_bit_cast(float, u);
}

// 8 chained MFMAs on one accumulator; A and W forced into arch VGPRs.
#define MFMA_CHAIN8(acc, A, W)                                          \
    asm volatile(                                                       \
        "s_nop 2\n\t"                                                   \
        "v_mfma_f32_16x16x32_bf16 %0, %1, %9, %0\n\t"                   \
        "v_mfma_f32_16x16x32_bf16 %0, %2, %10, %0\n\t"                  \
        "v_mfma_f32_16x16x32_bf16 %0, %3, %11, %0\n\t"                  \
        "v_mfma_f32_16x16x32_bf16 %0, %4, %12, %0\n\t"                  \
        "v_mfma_f32_16x16x32_bf16 %0, %5, %13, %0\n\t"                  \
        "v_mfma_f32_16x16x32_bf16 %0, %6, %14, %0\n\t"                  \
        "v_mfma_f32_16x16x32_bf16 %0, %7, %15, %0\n\t"                  \
        "v_mfma_f32_16x16x32_bf16 %0, %8, %16, %0"                      \
        : "+v"(acc)                                                     \
        : "v"((A)[0]), "v"((A)[1]), "v"((A)[2]), "v"((A)[3]),           \
          "v"((A)[4]), "v"((A)[5]), "v"((A)[6]), "v"((A)[7]),           \
          "v"((W)[0]), "v"((W)[1]), "v"((W)[2]), "v"((W)[3]),           \
          "v"((W)[4]), "v"((W)[5]), "v"((W)[6]), "v"((W)[7]))

__global__ __launch_bounds__(NT, 2) void rnn_kernel(
    const float* __restrict__ x,      // [B, T]
    const float* __restrict__ W_ih,   // [H, 1]
    const float* __restrict__ W_hh,   // [H, H]
    const float* __restrict__ b_ih,   // [H]
    const float* __restrict__ b_hh,   // [H]
    const float* __restrict__ W_out,  // [1, H]
    const float* __restrict__ b_out,  // [1]
    float* __restrict__ out)          // [B, T+FUT]
{
    __shared__ __align__(16) uint32_t hbuf[2][SPB * HID];   // packed (hi|lo), swizzled
    __shared__ __align__(16) float xstg[128][8];            // x chunk (cols 0..3 used)
    __shared__ __align__(16) float outbuf[2][SPB][68];      // o ring, padded

    const int tid  = threadIdx.x;
    const int lane = tid & 63;
    const int wid  = tid >> 6;        // wave w: owns cols 32w..32w+31
    const int l15  = lane & 15;
    const int g    = lane >> 4;       // lane quarter
    const int s0   = blockIdx.x * SPB;

    // ---- weight fragments (packed hi|lo), 160 VGPRs total ----
    // Slot map (A and B identical): G, slot s=8g+e -> real k=16G+4g+(e>>1),
    // parity e&1 selects hi/lo. W1 u32 = hi|lo<<16, W2 = lo|hi<<16.
    const int j0 = wid * 32 + l15;
    const int j1 = j0 + 16;
    u32x4 W1a[8], W2a[8], W1b[8], W2b[8], WoR[8];
    {
        const float* r0 = W_hh + (size_t)j0 * HID;
        const float* r1 = W_hh + (size_t)j1 * HID;
        #pragma unroll
        for (int G = 0; G < 8; ++G) {
            const int kb = G * 16 + g * 4;
            #pragma unroll
            for (int t = 0; t < 4; ++t) {
                const float wa = r0[kb + t];
                const float wb = r1[kb + t];
                const uint32_t ha = bf16_rn(wa);
                const uint32_t la = bf16_rn(wa - bf16f((unsigned short)ha));
                const uint32_t hb_ = bf16_rn(wb);
                const uint32_t lb = bf16_rn(wb - bf16f((unsigned short)hb_));
                W1a[G][t] = ha | (la << 16);
                W2a[G][t] = la | (ha << 16);
                W1b[G][t] = hb_ | (lb << 16);
                W2b[G][t] = lb | (hb_ << 16);
                // Wo: B col n=0 only (l15==0 lanes carry W_out over k)
                float wo = 0.0f;
                if (l15 == 0) wo = W_out[kb + t];
                const uint32_t ho = bf16_rn(wo);
                const uint32_t lo_ = bf16_rn(wo - bf16f((unsigned short)ho));
                WoR[G][t] = ho | (lo_ << 16);
            }
        }
    }
    const float bias0 = b_ih[j0] + b_hh[j0];
    const float bias1 = b_ih[j1] + b_hh[j1];
    const float wih0  = W_ih[j0], wih1 = W_ih[j1];
    const float bo    = b_out[0];

    // ---- LDS byte offsets; swizzle byte ^= (row&3)<<4 (rows 0..3 used) ----
    // A-read base: row l15, 16B at G*64 + g*16 (immediate per G).
    const int abase = l15 * 512 + ((g * 16) ^ ((l15 & 3) << 4));
    int woffA[4], woffB[4];
    #pragma unroll
    for (int r = 0; r < 4; ++r) {      // writes only from g==0 lanes: row=r
        const int swz = (r & 3) << 4;
        woffA[r] = r * 512 + ((4 * j0) ^ swz);
        woffB[r] = r * 512 + ((4 * j1) ^ swz);
    }

    for (int idx = tid; idx < SPB * HID; idx += NT) hbuf[0][idx] = 0;
    for (int idx = tid; idx < SPB * HID; idx += NT) hbuf[1][idx] = 0;
    __syncthreads();

    // A-fragments: zero once; exec-masked loads keep l15>=SPB lanes at zero.
    u32x4 A_[8];
    #pragma unroll
    for (int G = 0; G < 8; ++G) A_[G] = (u32x4){0, 0, 0, 0};

    for (int i = 0; i < NSTEP; ++i) {
        const int p = i & 1;

        // refill x chunk every 128 teacher steps
        if (i < TLEN && (i & 127) == 0) {
            #pragma unroll
            for (int pass = 0; pass < 2; ++pass) {
                const int idx = pass * NT + tid;
                const int t = idx & 127, s = idx >> 7;
                xstg[t][s] = x[(size_t)(s0 + s) * TLEN + (i + t)];
            }
            __syncthreads();
        }

        // flush a full 64-entry output ring (o_{i-65}..o_{i-2})
        if (i > 64 && (i & 63) == 1 && tid < 16 * SPB) {
            const int q = ((i - 65) >> 6) & 1;
            const int base = i - 65;
            const int s = tid >> 4, c4 = (tid & 15) * 4;
            const f32x4 v = *(const f32x4*)&outbuf[q][s][c4];
            *(f32x4*)&out[(size_t)(s0 + s) * NSTEP + base + c4] = v;
        }

        // A-fragments (rows >= SPB stay zero via exec mask)
        const char* hbp = (const char*)hbuf[p] + abase;
        if (l15 < SPB) {
            #pragma unroll
            for (int G = 0; G < 8; ++G)
                A_[G] = *(const u32x4*)(hbp + G * 64);
        }

        // 40 MFMA in 5 chains; weights/A in arch VGPRs, manual hazard nops
        f32x4 oa  = {0.f, 0.f, 0.f, 0.f};
        f32x4 p10 = {0.f,0.f,0.f,0.f}, p11 = p10, p20 = p10, p21 = p10;
        MFMA_CHAIN8(oa,  A_, WoR);
        MFMA_CHAIN8(p10, A_, W1a);
        MFMA_CHAIN8(p11, A_, W1b);
        MFMA_CHAIN8(p20, A_, W2a);
        MFMA_CHAIN8(p21, A_, W2b);
        // fence: no VALU read of any MFMA D-reg inside the wait-state window
        asm volatile("s_nop 7\n\ts_nop 7\n\ts_nop 7"
                     : "+v"(oa), "+v"(p10), "+v"(p11), "+v"(p20), "+v"(p21));

        // o_{i-1} = oa + bo (identical in all waves; rows r at lane 0)
        if (i > 0 && lane == 0 && wid == 0) {
            const int q = ((i - 1) >> 6) & 1;
            const int c = (i - 1) & 63;
            #pragma unroll
            for (int r = 0; r < 4; ++r) outbuf[q][r][c] = oa[r] + bo;
        }

        // per-row inputs (uniform branch)
        float in0, in1, in2, in3;
        if (i < TLEN) {
            const f32x4 xv = *(const f32x4*)&xstg[i & 127][0];
            in0 = xv[0]; in1 = xv[1]; in2 = xv[2]; in3 = xv[3];
        } else {
            in0 = __shfl(oa[0] + bo, 0);
            in1 = __shfl(oa[1] + bo, 0);
            in2 = __shfl(oa[2] + bo, 0);
            in3 = __shfl(oa[3] + bo, 0);
        }

        // epilogue: S, tanh, pack (hi|lo), writes from g==0 lanes (rows 0..3)
        char* hw = (char*)hbuf[p ^ 1];
        #pragma unroll
        for (int r = 0; r < 4; ++r) {
            const float inr = (r == 0) ? in0 : (r == 1) ? in1 : (r == 2) ? in2 : in3;
            const float S0 = p10[r] + p20[r] + bias0 + inr * wih0;
            const float S1 = p11[r] + p21[r] + bias1 + inr * wih1;
            const float h0 = fast_tanh(S0);
            const float h1 = fast_tanh(S1);
            uint32_t P;
            asm("v_cvt_pk_bf16_f32 %0, %1, %2" : "=v"(P) : "v"(h0), "v"(h1));
            const float hi0 = __builtin_bit_cast(float, P << 16);
            const float hi1 = __builtin_bit_cast(float, P & 0xffff0000u);
            const float lo0 = h0 - hi0;
            const float lo1 = h1 - hi1;
            uint32_t PL;
            asm("v_cvt_pk_bf16_f32 %0, %1, %2" : "=v"(PL) : "v"(lo0), "v"(lo1));
            if (g == 0) {
                *(uint32_t*)(hw + woffA[r]) = (P & 0xffffu) | (PL << 16);
                *(uint32_t*)(hw + woffB[r]) = (P >> 16) | (PL & 0xffff0000u);
            }
        }
        __syncthreads();   // the one per-step barrier
    }

    // tail: o_{NSTEP-1} from final state (in hbuf[0]); builtin MFMA is fine
    {
        const char* hbp = (const char*)hbuf[NSTEP & 1] + abase;
        if (l15 < SPB) {
            #pragma unroll
            for (int G = 0; G < 8; ++G)
                A_[G] = *(const u32x4*)(hbp + G * 64);
        }
        f32x4 oa = {0.f, 0.f, 0.f, 0.f};
        #pragma unroll
        for (int G = 0; G < 8; ++G)
            oa = __builtin_amdgcn_mfma_f32_16x16x32_bf16(asbf(A_[G]), asbf(WoR[G]), oa, 0, 0, 0);
        if (tid == 0) {
            #pragma unroll
            for (int r = 0; r < 4; ++r)
                outbuf[((NSTEP - 1) >> 6) & 1][r][63] = oa[r] + bo;
        }
    }
    __syncthreads();
    if (tid < 16 * SPB) {   // flush t = 1024..1087
        const int s = tid >> 4, c4 = (tid & 15) * 4;
        const f32x4 v = *(const f32x4*)&outbuf[0][s][c4];
        *(f32x4*)&out[(size_t)(s0 + s) * NSTEP + TLEN + c4] = v;
    }
}

extern "C" void kernel_launch(void* const* d_in, const int* in_sizes, int n_in,
                              void* d_out, int out_size, void* d_ws, size_t ws_size,
                              hipStream_t stream) {
    const float* x     = (const float*)d_in[0];
    const float* W_ih  = (const float*)d_in[1];
    const float* W_hh  = (const float*)d_in[2];
    const float* b_ih  = (const float*)d_in[3];
    const float* b_hh  = (const float*)d_in[4];
    const float* W_out = (const float*)d_in[5];
    const float* b_out = (const float*)d_in[6];
    float* out = (float*)d_out;

    dim3 grid(2048 / SPB);   // 512 blocks -> 2 per CU
    dim3 block(NT);
    rnn_kernel<<<grid, block, 0, stream>>>(x, W_ih, W_hh, b_ih, b_hh,
                                           W_out, b_out, out);
}